// Round 7
// baseline (163.387 us; speedup 1.0000x reference)
//
#include <hip/hip_runtime.h>

#define DEV __device__ __forceinline__

typedef __bf16 bf16x8 __attribute__((ext_vector_type(8)));
typedef __bf16 bf16x4 __attribute__((ext_vector_type(4)));
typedef float floatx4 __attribute__((ext_vector_type(4)));

// ---------------- K0: fused prep: cvt weights + pool ctx + transpose x ----
__global__ __launch_bounds__(256)
void prep_kernel(const float* __restrict__ Wq, const float* __restrict__ Wdy,
                 const float* __restrict__ ctx, const float* __restrict__ x,
                 __bf16* __restrict__ wqb, __bf16* __restrict__ wdyb,
                 float* __restrict__ kctx, __bf16* __restrict__ xt) {
  __shared__ float tile[64][65];
  int bid = blockIdx.x, t = threadIdx.x;
  if (bid < 256) {                       // weight cvt
    int i = bid * 256 + t;
    wqb[i]  = (__bf16)Wq[i];
    wdyb[i] = (__bf16)Wdy[i];
  } else if (bid < 512) {                // pool ctx 56x56 -> 7x7, one wave per (b,c)
    int bc = (bid - 256) * 4 + (t >> 6);
    const float* src = ctx + (size_t)bc * (56 * 56);
    int w = t & 63;
#pragma unroll
    for (int pi = 0; pi < 7; ++pi) {
      float s = 0.f;
      if (w < 56) {
#pragma unroll
        for (int di = 0; di < 8; ++di) s += src[(pi * 8 + di) * 56 + w];
      }
      s += __shfl_down(s, 4);
      s += __shfl_down(s, 2);
      s += __shfl_down(s, 1);
      if (w < 56 && (w & 7) == 0)
        kctx[(size_t)bc * 49 + pi * 7 + (w >> 3)] = s * (1.f / 64.f);
    }
  } else {                               // XT[b][n][c] = bf16(x[b][c][n])
    int idx = bid - 512;
    int b = idx >> 8, c0 = ((idx >> 6) & 3) * 64, n0 = (idx & 63) * 64;
    int lane = t & 63, rg = t >> 6;
    const float* src = x + ((size_t)b * 256 + c0) * 4096 + n0;
    for (int i = rg; i < 64; i += 4) tile[i][lane] = src[(size_t)i * 4096 + lane];
    __syncthreads();
    __bf16* dst = xt + ((size_t)b * 4096 + n0) * 256 + c0;
    for (int i = rg; i < 64; i += 4) dst[(size_t)i * 256 + lane] = (__bf16)tile[lane][i];
  }
}

// ---------------- K2: kf = LN(Wk @ kctx) per (b,l) ----------------
__global__ __launch_bounds__(256)
void kf_ln_kernel(const float* __restrict__ kctx, const float* __restrict__ Wk,
                  const float* __restrict__ gk, const float* __restrict__ bk,
                  float* __restrict__ kf) {
  int b = blockIdx.x / 49, l = blockIdx.x % 49;
  __shared__ float xs[256];
  __shared__ float r1[4], r2[4];
  int o = threadIdx.x;
  xs[o] = kctx[((size_t)b * 256 + o) * 49 + l];
  __syncthreads();
  const float* wrow = Wk + (size_t)o * 256;
  float acc = 0.f;
#pragma unroll 8
  for (int c = 0; c < 256; c += 4) {
    float4 wv = *(const float4*)(wrow + c);
    acc += wv.x * xs[c] + wv.y * xs[c + 1] + wv.z * xs[c + 2] + wv.w * xs[c + 3];
  }
  float s1 = acc, s2 = acc * acc;
#pragma unroll
  for (int off = 32; off > 0; off >>= 1) {
    s1 += __shfl_down(s1, off);
    s2 += __shfl_down(s2, off);
  }
  int wv_ = o >> 6, ln = o & 63;
  if (ln == 0) { r1[wv_] = s1; r2[wv_] = s2; }
  __syncthreads();
  float mu  = (r1[0] + r1[1] + r1[2] + r1[3]) * (1.f / 256.f);
  float var = (r2[0] + r2[1] + r2[2] + r2[3]) * (1.f / 256.f) - mu * mu;
  float rstd = rsqrtf(var + 1e-6f);
  kf[((size_t)b * 256 + o) * 49 + l] = (acc - mu) * rstd * gk[o] + bk[o];
}

// ------- K2b: kfpT[bg][m(80)][d(64)] = bf16( sum_l kf[b][g*64+d][l] * Wproj[m][l] ) -------
__global__ __launch_bounds__(256)
void kfp_kernel(const float* __restrict__ kf, const float* __restrict__ Wproj,
                __bf16* __restrict__ kfpT) {
  int bg = blockIdx.x; int b = bg >> 2, g = bg & 3;
  int m0 = blockIdx.y * 16;
  __shared__ float kfs[64][50];
  __shared__ float wps[16][50];
  int t = threadIdx.x;
  for (int i = t; i < 64 * 49; i += 256) {
    int d = i / 49, l = i % 49;
    kfs[d][l] = kf[((size_t)b * 256 + g * 64 + d) * 49 + l];
  }
  for (int i = t; i < 16 * 49; i += 256) {
    int m = i / 49, l = i % 49;
    wps[m][l] = (m0 + m < 74) ? Wproj[(m0 + m) * 49 + l] : 0.f;
  }
  __syncthreads();
  for (int i = t; i < 64 * 16; i += 256) {
    int d = i >> 4, m = i & 15;
    float s = 0.f;
    if (m0 + m < 74) {
#pragma unroll 7
      for (int l = 0; l < 49; ++l) s += kfs[d][l] * wps[m][l];
    }
    kfpT[(size_t)bg * 5120 + (m0 + m) * 64 + d] = (__bf16)s;
  }
}

// ---------------- softmax helpers (unchanged, proven) ----------------
DEV int rep_idx(int p, int kc, int t1, int sub) {
  return p < kc ? p : (p < t1 ? kc : p - sub);
}

template <int KK>
DEV void softmax_write(const float* wms, const float* rpb_s, __bf16* __restrict__ attnL,
                       int bg, int n_glob, int row) {
  constexpr int CNT = KK * KK;
  constexpr int RS  = 2 * KK - 1;
  constexpr int KC  = KK / 2;
  constexpr int T1  = KC + (64 - KK + 1);
  constexpr int SUB = 64 - KK;
  constexpr int MLO = (KK == 5) ? 0 : 25;
  constexpr int PW  = (KK == 5) ? 32 : 56;    // padded width (multiple of 8)
  int h = n_glob >> 6, w = n_glob & 63;
  int rh = rep_idx(63 - h, KC, T1, SUB);
  int rw = rep_idx(63 - w, KC, T1, SUB);
  float vals[CNT];
  float mx = -1e30f;
#pragma unroll
  for (int m = 0; m < CNT; ++m) {
    int ki = m / KK, kj = m % KK;
    float v = wms[row * 81 + MLO + m] + rpb_s[(rh + ki) * RS + rw + kj];
    vals[m] = v; mx = fmaxf(mx, v);
  }
  float ssum = 0.f;
#pragma unroll
  for (int m = 0; m < CNT; ++m) { float e = __expf(vals[m] - mx); vals[m] = e; ssum += e; }
  float inv = 1.f / ssum;
  __bf16 hv[PW];
#pragma unroll
  for (int m = 0; m < PW; ++m) hv[m] = (__bf16)(m < CNT ? vals[m] * inv : 0.f);
  __bf16* ap = attnL + ((size_t)bg * 4096 + n_glob) * 56;
#pragma unroll
  for (int i = 0; i < PW / 8; ++i) *(bf16x8*)(ap + i * 8) = *(bf16x8*)&hv[i * 8];
}

// ---------------- K3: fused q-GEMM + LN + QK-proj MFMA + softmax (512 thr, 8 waves) ----
__global__ __launch_bounds__(512, 1)
void qattn_kernel(const __bf16* __restrict__ Wb, const __bf16* __restrict__ XT,
                  const __bf16* __restrict__ kfpT,
                  const float* __restrict__ gq, const float* __restrict__ bq,
                  const float* __restrict__ rpb1, const float* __restrict__ rpb2,
                  __bf16* __restrict__ attnL) {
  __shared__ float wms[256 * 81];        // 82.9 KB, overlaid: As/Bs -> Aat -> wms
  __shared__ float rpb_s[500];           // rpb1 [0..161], rpb2 [162..499]
  __shared__ float gqs[256], bqs[256];
  __shared__ float red_s[4][64], red_q[4][64];
  __shared__ float st_mu[64], st_rs[64];
  __bf16* As  = (__bf16*)wms;            // [256 o][72 k] = 36864 B
  __bf16* Bs  = (__bf16*)wms + 256 * 72; // [64 n][72 k]  = 9216 B  (total 46 KB)
  __bf16* Aat = (__bf16*)wms;            // [4 g][64 n][72 d] = 36864 B

  int b  = blockIdx.z;
  int n0 = blockIdx.x * 64;
  int t  = threadIdx.x;
  int lane = t & 63, wv = t >> 6;
  int oq = wv & 3, nh = wv >> 2;         // o-quadrant, n-half
  int col = lane & 15, quad = lane >> 4;

  if (t < 256) {
    gqs[t] = gq[t] * 0.125f;             // SCALE folded
    bqs[t] = bq[t] * 0.125f;
  }
  for (int i = t; i < 162; i += 512) rpb_s[i] = rpb1[i];
  for (int i = t; i < 338; i += 512) rpb_s[162 + i] = rpb2[i];

  // hoist: kfpT B-fragments (global, L2-hot, independent of phases 1-2)
  bf16x8 fb2[2][5];
  const __bf16* kp = kfpT + (size_t)(b * 4 + oq) * 5120;
#pragma unroll
  for (int ks = 0; ks < 2; ++ks)
#pragma unroll
    for (int nt = 0; nt < 5; ++nt)
      fb2[ks][nt] = *(const bf16x8*)&kp[(nt * 16 + col) * 64 + ks * 32 + quad * 8];

  // ---- phase 1: q = Wq @ x, M=256(o) x N=64(n) x K=256, BK=64, reg-prefetched ----
  floatx4 acc[4][2];
#pragma unroll
  for (int i = 0; i < 4; ++i)
#pragma unroll
    for (int j = 0; j < 2; ++j) acc[i][j] = {0.f, 0.f, 0.f, 0.f};

  int rowA = t >> 1, kA = (t & 1) * 32;        // 256 W rows, 32 elems each
  int rowB = t >> 3, kB = (t & 7) * 8;         // 64 XT rows, 8 elems each
  const __bf16* wp = Wb + (size_t)rowA * 256 + kA;
  const __bf16* xp = XT + ((size_t)b * 4096 + n0 + rowB) * 256 + kB;
  bf16x8 ra0 = *(const bf16x8*)wp;
  bf16x8 ra1 = *(const bf16x8*)(wp + 8);
  bf16x8 ra2 = *(const bf16x8*)(wp + 16);
  bf16x8 ra3 = *(const bf16x8*)(wp + 24);
  bf16x8 rb  = *(const bf16x8*)xp;

  for (int c0 = 0; c0 < 256; c0 += 64) {
    *(bf16x8*)&As[rowA * 72 + kA]      = ra0;
    *(bf16x8*)&As[rowA * 72 + kA + 8]  = ra1;
    *(bf16x8*)&As[rowA * 72 + kA + 16] = ra2;
    *(bf16x8*)&As[rowA * 72 + kA + 24] = ra3;
    *(bf16x8*)&Bs[rowB * 72 + kB]      = rb;
    __syncthreads();
    if (c0 + 64 < 256) {                 // prefetch next K-tile; hides under 16 MFMA
      ra0 = *(const bf16x8*)(wp + c0 + 64);
      ra1 = *(const bf16x8*)(wp + c0 + 72);
      ra2 = *(const bf16x8*)(wp + c0 + 80);
      ra3 = *(const bf16x8*)(wp + c0 + 88);
      rb  = *(const bf16x8*)(xp + c0 + 64);
    }
    bf16x8 fa[2][4], fb[2][2];
#pragma unroll
    for (int ks = 0; ks < 2; ++ks) {
#pragma unroll
      for (int i = 0; i < 4; ++i)
        fa[ks][i] = *(const bf16x8*)&As[(oq * 64 + i * 16 + col) * 72 + ks * 32 + quad * 8];
#pragma unroll
      for (int j = 0; j < 2; ++j)
        fb[ks][j] = *(const bf16x8*)&Bs[(nh * 32 + j * 16 + col) * 72 + ks * 32 + quad * 8];
    }
#pragma unroll
    for (int ks = 0; ks < 2; ++ks)
#pragma unroll
      for (int i = 0; i < 4; ++i)
#pragma unroll
        for (int j = 0; j < 2; ++j)
          acc[i][j] = __builtin_amdgcn_mfma_f32_16x16x32_bf16(fa[ks][i], fb[ks][j], acc[i][j], 0, 0, 0);
    __syncthreads();
  }

  // ---- phase 2: LN stats over o (exact f32) ----
#pragma unroll
  for (int j = 0; j < 2; ++j) {
    float s = 0.f, q = 0.f;
#pragma unroll
    for (int i = 0; i < 4; ++i)
#pragma unroll
      for (int r = 0; r < 4; ++r) { float v = acc[i][j][r]; s += v; q += v * v; }
    s += __shfl_xor(s, 16); s += __shfl_xor(s, 32);   // reduce over quad -> full 64-o
    q += __shfl_xor(q, 16); q += __shfl_xor(q, 32);
    if (quad == 0) {
      red_s[oq][nh * 32 + j * 16 + col] = s;
      red_q[oq][nh * 32 + j * 16 + col] = q;
    }
  }
  __syncthreads();
  if (t < 64) {
    float s = red_s[0][t] + red_s[1][t] + red_s[2][t] + red_s[3][t];
    float q = red_q[0][t] + red_q[1][t] + red_q[2][t] + red_q[3][t];
    float mu  = s * (1.f / 256.f);
    float var = q * (1.f / 256.f) - mu * mu;
    st_mu[t] = mu;
    st_rs[t] = rsqrtf(var + 1e-6f);
  }
  __syncthreads();

  // ---- phase 3: q-hat -> Aat (A-fragment layout), then attn MFMA ----
#pragma unroll
  for (int j = 0; j < 2; ++j) {
    int n_loc = nh * 32 + j * 16 + col;
    float mu = st_mu[n_loc], rs = st_rs[n_loc];
#pragma unroll
    for (int i = 0; i < 4; ++i) {
      __bf16 pk[4];
#pragma unroll
      for (int r = 0; r < 4; ++r) {
        int o = oq * 64 + i * 16 + quad * 4 + r;
        pk[r] = (__bf16)((acc[i][j][r] - mu) * rs * gqs[o] + bqs[o]);
      }
      *(bf16x4*)&Aat[((size_t)(oq * 64 + n_loc)) * 72 + i * 16 + quad * 4] = *(bf16x4*)pk;
    }
  }
  __syncthreads();

  // attn MFMA: per head-group g = oq; 2 waves/g, each 32 n x 80 m x K=64
  bf16x8 fa2[2][2];
#pragma unroll
  for (int ks = 0; ks < 2; ++ks)
#pragma unroll
    for (int a = 0; a < 2; ++a)
      fa2[ks][a] = *(const bf16x8*)&Aat[((size_t)(oq * 64 + nh * 32 + a * 16 + col)) * 72 + ks * 32 + quad * 8];
  floatx4 acc2[2][5];
#pragma unroll
  for (int a = 0; a < 2; ++a)
#pragma unroll
    for (int nt = 0; nt < 5; ++nt) acc2[a][nt] = {0.f, 0.f, 0.f, 0.f};
#pragma unroll
  for (int ks = 0; ks < 2; ++ks)
#pragma unroll
    for (int a = 0; a < 2; ++a)
#pragma unroll
      for (int nt = 0; nt < 5; ++nt)
        acc2[a][nt] = __builtin_amdgcn_mfma_f32_16x16x32_bf16(fa2[ks][a], fb2[ks][nt], acc2[a][nt], 0, 0, 0);
  __syncthreads();   // all Aat reads done before wms overwrite

#pragma unroll
  for (int a = 0; a < 2; ++a)
#pragma unroll
    for (int nt = 0; nt < 5; ++nt)
#pragma unroll
      for (int r = 0; r < 4; ++r)
        wms[(oq * 64 + nh * 32 + a * 16 + quad * 4 + r) * 81 + nt * 16 + col] = acc2[a][nt][r];
  __syncthreads();

  // ---- phase 4: softmax, one row per thread (256 rows = 64 n x 4 g) ----
  if (t < 256) {
    int g2 = t >> 6;
    int n_glob = n0 + (t & 63);
    int bg = b * 4 + g2;
    if (g2 < 2) softmax_write<5>(wms, rpb_s + g2 * 81,              attnL, bg, n_glob, t);
    else        softmax_write<7>(wms, rpb_s + 162 + (g2 - 2) * 169, attnL, bg, n_glob, t);
  }
}

// ---------------- K-out: bf16 MFMA 1x1 conv, 128x64 tile -> 2 blocks/CU ----------------
template <int MODE>
__global__ __launch_bounds__(256, 2)
void conv_mfma_kernel(const __bf16* __restrict__ Wb, const __bf16* __restrict__ Xin,
                      void* __restrict__ Yout, float* __restrict__ stats,
                      const float* __restrict__ bn_g, const float* __restrict__ bn_b) {
  int b  = blockIdx.z;
  int n0 = blockIdx.x * 64;
  int o0 = blockIdx.y * 128;
  __shared__ __bf16 As[128 * 32];   // [m][k]
  __shared__ __bf16 Bs[64 * 32];    // [n][k]
  int t = threadIdx.x;
  int lane = t & 63, wv = t >> 6;
  int mq = (wv & 1) * 64, nq = (wv >> 1) * 32;
  int col = lane & 15, quad = lane >> 4;
  floatx4 acc[4][2];
#pragma unroll
  for (int i = 0; i < 4; ++i)
#pragma unroll
    for (int j = 0; j < 2; ++j) acc[i][j] = {0.f, 0.f, 0.f, 0.f};
  int sm = t >> 1, sk = (t & 1) << 4;      // A: 128 rows x 16 elems
  int snB = t >> 2, kB8 = (t & 3) * 8;     // B: 64 rows x 8 elems
  const __bf16* wp = Wb + (size_t)(o0 + sm) * 256 + sk;
  auto xaddr = [&](int c0) -> const __bf16* {
    if (MODE == 0) {
      return Xin + ((size_t)b * 4096 + n0 + snB) * 256 + c0 + kB8;
    } else {
      int c = c0 + kB8, g = c >> 6, c64 = c & 63;   // 8-elem load stays in-plane
      return Xin + (((size_t)(b * 4 + g)) * 4096 + n0 + snB) * 64 + c64;
    }
  };
  bf16x8 wa0 = *(const bf16x8*)wp;
  bf16x8 wa1 = *(const bf16x8*)(wp + 8);
  bf16x8 xb0 = *(const bf16x8*)xaddr(0);
  for (int c0 = 0; c0 < 256; c0 += 32) {
    *(bf16x8*)&As[sm * 32 + sk]     = wa0;
    *(bf16x8*)&As[sm * 32 + sk + 8] = wa1;
    *(bf16x8*)&Bs[snB * 32 + kB8]   = xb0;
    __syncthreads();
    if (c0 + 32 < 256) {               // prefetch next K-tile; hides under MFMA
      wa0 = *(const bf16x8*)(wp + c0 + 32);
      wa1 = *(const bf16x8*)(wp + c0 + 40);
      xb0 = *(const bf16x8*)xaddr(c0 + 32);
    }
    bf16x8 fa[4], fb[2];
#pragma unroll
    for (int i = 0; i < 4; ++i)
      fa[i] = *(const bf16x8*)&As[(mq + i * 16 + col) * 32 + quad * 8];
#pragma unroll
    for (int j = 0; j < 2; ++j)
      fb[j] = *(const bf16x8*)&Bs[(nq + j * 16 + col) * 32 + quad * 8];
#pragma unroll
    for (int i = 0; i < 4; ++i)
#pragma unroll
      for (int j = 0; j < 2; ++j)
        acc[i][j] = __builtin_amdgcn_mfma_f32_16x16x32_bf16(fa[i], fb[j], acc[i][j], 0, 0, 0);
    __syncthreads();
  }
  {
    float* Yf = (float*)Yout + (size_t)b * 256 * 4096;
#pragma unroll
    for (int i = 0; i < 4; ++i) {
#pragma unroll
      for (int r = 0; r < 4; ++r) {
        int o = o0 + mq + i * 16 + quad * 4 + r;
        float scale = bn_g[o] * 0.9999950000374997f;  // rsqrt(1 + 1e-5)
        float shift = bn_b[o];
        float* yrow = Yf + (size_t)o * 4096 + n0 + nq + col;
#pragma unroll
        for (int j = 0; j < 2; ++j) yrow[j * 16] = acc[i][j][r] * scale + shift;
      }
    }
  }
}

// ------- K5: na2d AV, f32 LDS slab, h-PAIRED inner loop (shares row reads) -------
// block = (bg, 8-h slab, ch-half), 512 thr. xs f32 [ROWS<=14][64 w][36 ch].
// thread: w = t&63, cg = (t>>6)&3 (8 ch), hh = t>>8 (2 pair-groups of 2 h-pairs).
DEV void fma8(float* acc, float a, float4 v0, float4 v1) {
  acc[0] += a * v0.x; acc[1] += a * v0.y; acc[2] += a * v0.z; acc[3] += a * v0.w;
  acc[4] += a * v1.x; acc[5] += a * v1.y; acc[6] += a * v1.z; acc[7] += a * v1.w;
}

template <int KK>
DEV void na2d_body8(const __bf16* __restrict__ attnL, const __bf16* __restrict__ XT,
                    __bf16* __restrict__ midT, float* xs, int bg, int h0, int chalf, int t) {
  constexpr int KC = KK / 2, SMAX = 64 - KK;
  constexpr int ROWS = KK + 7;
  constexpr int PW = (KK == 5) ? 32 : 56;
  constexpr int NV = PW / 8;
  int b = bg >> 2, g = bg & 3;
  int si0 = min(max(h0 - KC, 0), SMAX);
  // stage ROWS rows of the 32-ch half into LDS as f32 (convert once)
  {
    int sn = t & 63, sc8 = (t >> 6) & 3, rh = t >> 8;
    const __bf16* src = XT + ((size_t)b * 4096 + sn) * 256 + g * 64 + chalf * 32 + sc8 * 8;
    for (int r = rh; r < ROWS; r += 2) {
      int gr = min(si0 + r, 63);
      bf16x8 v = *(const bf16x8*)(src + (size_t)gr * 64 * 256);
      float f[8];
#pragma unroll
      for (int e = 0; e < 8; ++e) f[e] = (float)v[e];
      float* d = &xs[(r * 64 + sn) * 36 + sc8 * 8];
      *(float4*)d       = *(float4*)&f[0];
      *(float4*)(d + 4) = *(float4*)&f[4];
    }
  }
  __syncthreads();
  int w = t & 63, cg = (t >> 6) & 3, hh = t >> 8;
  int sj = min(max(w - KC, 0), SMAX);
  const float* xbase = &xs[sj * 36 + cg * 8];
#pragma unroll
  for (int pr = 0; pr < 2; ++pr) {           // two h-pairs per thread
    int he = h0 + hh * 4 + pr * 2;           // even h of the pair
    int b0 = min(max(he - KC, 0), SMAX) - si0;
    int b1 = min(max(he + 1 - KC, 0), SMAX) - si0;   // b1 - b0 in {0,1}, wave-uniform
    bf16x8 av0[NV], av1[NV];
    const __bf16* ap0 = attnL + ((size_t)bg * 4096 + he * 64 + w) * 56;
#pragma unroll
    for (int i = 0; i < NV; ++i) {
      av0[i] = *(const bf16x8*)(ap0 + i * 8);
      av1[i] = *(const bf16x8*)(ap0 + 64 * 56 + i * 8);
    }
    float ac0[8] = {}, ac1[8] = {};
    if (b1 != b0) {                          // interior: offset 1, shared row reads
#pragma unroll
      for (int r = 0; r <= KK; ++r) {
        const float* xr = xbase + (b0 + r) * (64 * 36);
#pragma unroll
        for (int q = 0; q < KK; ++q) {
          float4 v0 = *(const float4*)(xr + q * 36);
          float4 v1 = *(const float4*)(xr + q * 36 + 4);
          if (r < KK)  { int m = r * KK + q;       float a = (float)av0[m >> 3][m & 7]; fma8(ac0, a, v0, v1); }
          if (r >= 1)  { int m = (r - 1) * KK + q; float a = (float)av1[m >> 3][m & 7]; fma8(ac1, a, v0, v1); }
        }
      }
    } else {                                 // clamped edge: same window for both h
#pragma unroll
      for (int r = 0; r < KK; ++r) {
        const float* xr = xbase + (b0 + r) * (64 * 36);
#pragma unroll
        for (int q = 0; q < KK; ++q) {
          float4 v0 = *(const float4*)(xr + q * 36);
          float4 v1 = *(const float4*)(xr + q * 36 + 4);
          int m = r * KK + q;
          float a0 = (float)av0[m >> 3][m & 7];
          float a1 = (float)av1[m >> 3][m & 7];
          fma8(ac0, a0, v0, v1);
          fma8(ac1, a1, v0, v1);
        }
      }
    }
    __bf16 hv[8];
#pragma unroll
    for (int e = 0; e < 8; ++e) hv[e] = (__bf16)ac0[e];
    *(bf16x8*)&midT[((size_t)bg * 4096 + he * 64 + w) * 64 + chalf * 32 + cg * 8] = *(bf16x8*)hv;
#pragma unroll
    for (int e = 0; e < 8; ++e) hv[e] = (__bf16)ac1[e];
    *(bf16x8*)&midT[((size_t)bg * 4096 + (he + 1) * 64 + w) * 64 + chalf * 32 + cg * 8] = *(bf16x8*)hv;
  }
}

__global__ __launch_bounds__(512, 1)
void na2d_kernel(const __bf16* __restrict__ attnL, const __bf16* __restrict__ XT,
                 __bf16* __restrict__ midT) {
  __shared__ float xs[14 * 64 * 36];   // 129 KB (KK=7 uses 14 rows, KK=5 uses 12)
  int bg = blockIdx.x, h0 = blockIdx.y * 8, chalf = blockIdx.z, t = threadIdx.x;
  if ((bg & 3) < 2) na2d_body8<5>(attnL, XT, midT, xs, bg, h0, chalf, t);
  else              na2d_body8<7>(attnL, XT, midT, xs, bg, h0, chalf, t);
}

// ---------------- launch ----------------
extern "C" void kernel_launch(void* const* d_in, const int* in_sizes, int n_in,
                              void* d_out, int out_size, void* d_ws, size_t ws_size,
                              hipStream_t stream) {
  const float* x     = (const float*)d_in[0];
  const float* ctx   = (const float*)d_in[1];
  const float* Wq    = (const float*)d_in[2];
  const float* gq    = (const float*)d_in[3];
  const float* bq    = (const float*)d_in[4];
  const float* Wk    = (const float*)d_in[5];
  const float* gk    = (const float*)d_in[6];
  const float* bk    = (const float*)d_in[7];
  const float* Wproj = (const float*)d_in[8];
  const float* rpb1  = (const float*)d_in[9];
  const float* rpb2  = (const float*)d_in[10];
  const float* Wdy   = (const float*)d_in[11];
  const float* bn_g  = (const float*)d_in[12];
  const float* bn_b  = (const float*)d_in[13];
  float* out = (float*)d_out;

  float* ws     = (float*)d_ws;
  float* kctx   = ws;                          // 50176 f
  float* kf     = kctx + 50176;                // 50176 f
  __bf16* attnL = (__bf16*)(kf + 50176);       // 16*4096*56 = 3670016 bf16
  __bf16* wqb   = attnL + 3670016;             // 65536 bf16
  __bf16* wdyb  = wqb + 65536;                 // 65536 bf16
  __bf16* kfpT  = wdyb + 65536;                // 16*80*64 = 81920 bf16
  __bf16* XT    = kfpT + 81920;                // 4194304 bf16
  __bf16* midT  = XT + 4194304;                // 4194304 bf16 (planar [bg][n][64])

  prep_kernel<<<dim3(1536), dim3(256), 0, stream>>>(Wq, Wdy, ctx, x, wqb, wdyb, kctx, XT);
  kf_ln_kernel<<<dim3(196), dim3(256), 0, stream>>>(kctx, Wk, gk, bk, kf);
  kfp_kernel<<<dim3(16, 5), dim3(256), 0, stream>>>(kf, Wproj, kfpT);
  qattn_kernel<<<dim3(64, 1, 4), dim3(512), 0, stream>>>(wqb, XT, kfpT, gq, bq, rpb1, rpb2, attnL);
  na2d_kernel<<<dim3(16, 8, 2), dim3(512), 0, stream>>>(attnL, XT, midT);
  conv_mfma_kernel<1><<<dim3(64, 2, 4), dim3(256), 0, stream>>>(wdyb, midT, out, nullptr, bn_g, bn_b);
}

// Round 8
// 154.233 us; speedup vs baseline: 1.0593x; 1.0593x over previous
//
#include <hip/hip_runtime.h>

#define DEV __device__ __forceinline__

typedef __bf16 bf16x8 __attribute__((ext_vector_type(8)));
typedef __bf16 bf16x4 __attribute__((ext_vector_type(4)));
typedef float floatx4 __attribute__((ext_vector_type(4)));

// ---------------- K0: fused prep: cvt weights + pool ctx + transpose x ----
__global__ __launch_bounds__(256)
void prep_kernel(const float* __restrict__ Wq, const float* __restrict__ Wdy,
                 const float* __restrict__ ctx, const float* __restrict__ x,
                 __bf16* __restrict__ wqb, __bf16* __restrict__ wdyb,
                 float* __restrict__ kctx, __bf16* __restrict__ xt) {
  __shared__ float tile[64][65];
  int bid = blockIdx.x, t = threadIdx.x;
  if (bid < 256) {                       // weight cvt
    int i = bid * 256 + t;
    wqb[i]  = (__bf16)Wq[i];
    wdyb[i] = (__bf16)Wdy[i];
  } else if (bid < 512) {                // pool ctx 56x56 -> 7x7, one wave per (b,c)
    int bc = (bid - 256) * 4 + (t >> 6);
    const float* src = ctx + (size_t)bc * (56 * 56);
    int w = t & 63;
#pragma unroll
    for (int pi = 0; pi < 7; ++pi) {
      float s = 0.f;
      if (w < 56) {
#pragma unroll
        for (int di = 0; di < 8; ++di) s += src[(pi * 8 + di) * 56 + w];
      }
      s += __shfl_down(s, 4);
      s += __shfl_down(s, 2);
      s += __shfl_down(s, 1);
      if (w < 56 && (w & 7) == 0)
        kctx[(size_t)bc * 49 + pi * 7 + (w >> 3)] = s * (1.f / 64.f);
    }
  } else {                               // XT[b][n][c] = bf16(x[b][c][n])
    int idx = bid - 512;
    int b = idx >> 8, c0 = ((idx >> 6) & 3) * 64, n0 = (idx & 63) * 64;
    int lane = t & 63, rg = t >> 6;
    const float* src = x + ((size_t)b * 256 + c0) * 4096 + n0;
    for (int i = rg; i < 64; i += 4) tile[i][lane] = src[(size_t)i * 4096 + lane];
    __syncthreads();
    __bf16* dst = xt + ((size_t)b * 4096 + n0) * 256 + c0;
    for (int i = rg; i < 64; i += 4) dst[(size_t)i * 256 + lane] = (__bf16)tile[lane][i];
  }
}

// ---------------- K2: kf = LN(Wk @ kctx) per (b,l) ----------------
__global__ __launch_bounds__(256)
void kf_ln_kernel(const float* __restrict__ kctx, const float* __restrict__ Wk,
                  const float* __restrict__ gk, const float* __restrict__ bk,
                  float* __restrict__ kf) {
  int b = blockIdx.x / 49, l = blockIdx.x % 49;
  __shared__ float xs[256];
  __shared__ float r1[4], r2[4];
  int o = threadIdx.x;
  xs[o] = kctx[((size_t)b * 256 + o) * 49 + l];
  __syncthreads();
  const float* wrow = Wk + (size_t)o * 256;
  float acc = 0.f;
#pragma unroll 8
  for (int c = 0; c < 256; c += 4) {
    float4 wv = *(const float4*)(wrow + c);
    acc += wv.x * xs[c] + wv.y * xs[c + 1] + wv.z * xs[c + 2] + wv.w * xs[c + 3];
  }
  float s1 = acc, s2 = acc * acc;
#pragma unroll
  for (int off = 32; off > 0; off >>= 1) {
    s1 += __shfl_down(s1, off);
    s2 += __shfl_down(s2, off);
  }
  int wv_ = o >> 6, ln = o & 63;
  if (ln == 0) { r1[wv_] = s1; r2[wv_] = s2; }
  __syncthreads();
  float mu  = (r1[0] + r1[1] + r1[2] + r1[3]) * (1.f / 256.f);
  float var = (r2[0] + r2[1] + r2[2] + r2[3]) * (1.f / 256.f) - mu * mu;
  float rstd = rsqrtf(var + 1e-6f);
  kf[((size_t)b * 256 + o) * 49 + l] = (acc - mu) * rstd * gk[o] + bk[o];
}

// ------- K2b: kfpT[bg][m(80)][d(64)] = bf16( sum_l kf[b][g*64+d][l] * Wproj[m][l] ) -------
__global__ __launch_bounds__(256)
void kfp_kernel(const float* __restrict__ kf, const float* __restrict__ Wproj,
                __bf16* __restrict__ kfpT) {
  int bg = blockIdx.x; int b = bg >> 2, g = bg & 3;
  int m0 = blockIdx.y * 16;
  __shared__ float kfs[64][50];
  __shared__ float wps[16][50];
  int t = threadIdx.x;
  for (int i = t; i < 64 * 49; i += 256) {
    int d = i / 49, l = i % 49;
    kfs[d][l] = kf[((size_t)b * 256 + g * 64 + d) * 49 + l];
  }
  for (int i = t; i < 16 * 49; i += 256) {
    int m = i / 49, l = i % 49;
    wps[m][l] = (m0 + m < 74) ? Wproj[(m0 + m) * 49 + l] : 0.f;
  }
  __syncthreads();
  for (int i = t; i < 64 * 16; i += 256) {
    int d = i >> 4, m = i & 15;
    float s = 0.f;
    if (m0 + m < 74) {
#pragma unroll 7
      for (int l = 0; l < 49; ++l) s += kfs[d][l] * wps[m][l];
    }
    kfpT[(size_t)bg * 5120 + (m0 + m) * 64 + d] = (__bf16)s;
  }
}

// ---------------- softmax helpers (unchanged, proven) ----------------
DEV int rep_idx(int p, int kc, int t1, int sub) {
  return p < kc ? p : (p < t1 ? kc : p - sub);
}

template <int KK>
DEV void softmax_write(const float* wms, const float* rpb_s, __bf16* __restrict__ attnL,
                       int bg, int n_glob, int row) {
  constexpr int CNT = KK * KK;
  constexpr int RS  = 2 * KK - 1;
  constexpr int KC  = KK / 2;
  constexpr int T1  = KC + (64 - KK + 1);
  constexpr int SUB = 64 - KK;
  constexpr int MLO = (KK == 5) ? 0 : 25;
  constexpr int PW  = (KK == 5) ? 32 : 56;    // padded width (multiple of 8)
  int h = n_glob >> 6, w = n_glob & 63;
  int rh = rep_idx(63 - h, KC, T1, SUB);
  int rw = rep_idx(63 - w, KC, T1, SUB);
  float vals[CNT];
  float mx = -1e30f;
#pragma unroll
  for (int m = 0; m < CNT; ++m) {
    int ki = m / KK, kj = m % KK;
    float v = wms[row * 81 + MLO + m] + rpb_s[(rh + ki) * RS + rw + kj];
    vals[m] = v; mx = fmaxf(mx, v);
  }
  float ssum = 0.f;
#pragma unroll
  for (int m = 0; m < CNT; ++m) { float e = __expf(vals[m] - mx); vals[m] = e; ssum += e; }
  float inv = 1.f / ssum;
  __bf16 hv[PW];
#pragma unroll
  for (int m = 0; m < PW; ++m) hv[m] = (__bf16)(m < CNT ? vals[m] * inv : 0.f);
  __bf16* ap = attnL + ((size_t)bg * 4096 + n_glob) * 56;
#pragma unroll
  for (int i = 0; i < PW / 8; ++i) *(bf16x8*)(ap + i * 8) = *(bf16x8*)&hv[i * 8];
}

// ---------------- K3: fused q-GEMM + LN + QK-proj MFMA + softmax (512 thr, 8 waves) ----
// (exact R6 state: no kfpT hoist)
__global__ __launch_bounds__(512, 1)
void qattn_kernel(const __bf16* __restrict__ Wb, const __bf16* __restrict__ XT,
                  const __bf16* __restrict__ kfpT,
                  const float* __restrict__ gq, const float* __restrict__ bq,
                  const float* __restrict__ rpb1, const float* __restrict__ rpb2,
                  __bf16* __restrict__ attnL) {
  __shared__ float wms[256 * 81];        // 82.9 KB, overlaid: As/Bs -> Aat -> wms
  __shared__ float rpb_s[500];           // rpb1 [0..161], rpb2 [162..499]
  __shared__ float gqs[256], bqs[256];
  __shared__ float red_s[4][64], red_q[4][64];
  __shared__ float st_mu[64], st_rs[64];
  __bf16* As  = (__bf16*)wms;            // [256 o][72 k] = 36864 B
  __bf16* Bs  = (__bf16*)wms + 256 * 72; // [64 n][72 k]  = 9216 B  (total 46 KB)
  __bf16* Aat = (__bf16*)wms;            // [4 g][64 n][72 d] = 36864 B

  int b  = blockIdx.z;
  int n0 = blockIdx.x * 64;
  int t  = threadIdx.x;
  int lane = t & 63, wv = t >> 6;
  int oq = wv & 3, nh = wv >> 2;         // o-quadrant, n-half
  int col = lane & 15, quad = lane >> 4;

  if (t < 256) {
    gqs[t] = gq[t] * 0.125f;             // SCALE folded
    bqs[t] = bq[t] * 0.125f;
  }
  for (int i = t; i < 162; i += 512) rpb_s[i] = rpb1[i];
  for (int i = t; i < 338; i += 512) rpb_s[162 + i] = rpb2[i];

  // ---- phase 1: q = Wq @ x, M=256(o) x N=64(n) x K=256, BK=64, reg-prefetched ----
  floatx4 acc[4][2];
#pragma unroll
  for (int i = 0; i < 4; ++i)
#pragma unroll
    for (int j = 0; j < 2; ++j) acc[i][j] = {0.f, 0.f, 0.f, 0.f};

  int rowA = t >> 1, kA = (t & 1) * 32;        // 256 W rows, 32 elems each
  int rowB = t >> 3, kB = (t & 7) * 8;         // 64 XT rows, 8 elems each
  const __bf16* wp = Wb + (size_t)rowA * 256 + kA;
  const __bf16* xp = XT + ((size_t)b * 4096 + n0 + rowB) * 256 + kB;
  bf16x8 ra0 = *(const bf16x8*)wp;
  bf16x8 ra1 = *(const bf16x8*)(wp + 8);
  bf16x8 ra2 = *(const bf16x8*)(wp + 16);
  bf16x8 ra3 = *(const bf16x8*)(wp + 24);
  bf16x8 rb  = *(const bf16x8*)xp;

  for (int c0 = 0; c0 < 256; c0 += 64) {
    *(bf16x8*)&As[rowA * 72 + kA]      = ra0;
    *(bf16x8*)&As[rowA * 72 + kA + 8]  = ra1;
    *(bf16x8*)&As[rowA * 72 + kA + 16] = ra2;
    *(bf16x8*)&As[rowA * 72 + kA + 24] = ra3;
    *(bf16x8*)&Bs[rowB * 72 + kB]      = rb;
    __syncthreads();
    if (c0 + 64 < 256) {                 // prefetch next K-tile; hides under 16 MFMA
      ra0 = *(const bf16x8*)(wp + c0 + 64);
      ra1 = *(const bf16x8*)(wp + c0 + 72);
      ra2 = *(const bf16x8*)(wp + c0 + 80);
      ra3 = *(const bf16x8*)(wp + c0 + 88);
      rb  = *(const bf16x8*)(xp + c0 + 64);
    }
    bf16x8 fa[2][4], fb[2][2];
#pragma unroll
    for (int ks = 0; ks < 2; ++ks) {
#pragma unroll
      for (int i = 0; i < 4; ++i)
        fa[ks][i] = *(const bf16x8*)&As[(oq * 64 + i * 16 + col) * 72 + ks * 32 + quad * 8];
#pragma unroll
      for (int j = 0; j < 2; ++j)
        fb[ks][j] = *(const bf16x8*)&Bs[(nh * 32 + j * 16 + col) * 72 + ks * 32 + quad * 8];
    }
#pragma unroll
    for (int ks = 0; ks < 2; ++ks)
#pragma unroll
      for (int i = 0; i < 4; ++i)
#pragma unroll
        for (int j = 0; j < 2; ++j)
          acc[i][j] = __builtin_amdgcn_mfma_f32_16x16x32_bf16(fa[ks][i], fb[ks][j], acc[i][j], 0, 0, 0);
    __syncthreads();
  }

  // ---- phase 2: LN stats over o (exact f32) ----
#pragma unroll
  for (int j = 0; j < 2; ++j) {
    float s = 0.f, q = 0.f;
#pragma unroll
    for (int i = 0; i < 4; ++i)
#pragma unroll
      for (int r = 0; r < 4; ++r) { float v = acc[i][j][r]; s += v; q += v * v; }
    s += __shfl_xor(s, 16); s += __shfl_xor(s, 32);   // reduce over quad -> full 64-o
    q += __shfl_xor(q, 16); q += __shfl_xor(q, 32);
    if (quad == 0) {
      red_s[oq][nh * 32 + j * 16 + col] = s;
      red_q[oq][nh * 32 + j * 16 + col] = q;
    }
  }
  __syncthreads();
  if (t < 64) {
    float s = red_s[0][t] + red_s[1][t] + red_s[2][t] + red_s[3][t];
    float q = red_q[0][t] + red_q[1][t] + red_q[2][t] + red_q[3][t];
    float mu  = s * (1.f / 256.f);
    float var = q * (1.f / 256.f) - mu * mu;
    st_mu[t] = mu;
    st_rs[t] = rsqrtf(var + 1e-6f);
  }
  __syncthreads();

  // ---- phase 3: q-hat -> Aat (A-fragment layout), then attn MFMA ----
#pragma unroll
  for (int j = 0; j < 2; ++j) {
    int n_loc = nh * 32 + j * 16 + col;
    float mu = st_mu[n_loc], rs = st_rs[n_loc];
#pragma unroll
    for (int i = 0; i < 4; ++i) {
      __bf16 pk[4];
#pragma unroll
      for (int r = 0; r < 4; ++r) {
        int o = oq * 64 + i * 16 + quad * 4 + r;
        pk[r] = (__bf16)((acc[i][j][r] - mu) * rs * gqs[o] + bqs[o]);
      }
      *(bf16x4*)&Aat[((size_t)(oq * 64 + n_loc)) * 72 + i * 16 + quad * 4] = *(bf16x4*)pk;
    }
  }
  __syncthreads();

  // attn MFMA: per head-group g = oq; 2 waves/g, each 32 n x 80 m x K=64
  bf16x8 fa2[2][2], fb2[2][5];
  const __bf16* kp = kfpT + (size_t)(b * 4 + oq) * 5120;   // L2-hot, 10 KB
#pragma unroll
  for (int ks = 0; ks < 2; ++ks) {
#pragma unroll
    for (int a = 0; a < 2; ++a)
      fa2[ks][a] = *(const bf16x8*)&Aat[((size_t)(oq * 64 + nh * 32 + a * 16 + col)) * 72 + ks * 32 + quad * 8];
#pragma unroll
    for (int nt = 0; nt < 5; ++nt)
      fb2[ks][nt] = *(const bf16x8*)&kp[(nt * 16 + col) * 64 + ks * 32 + quad * 8];
  }
  floatx4 acc2[2][5];
#pragma unroll
  for (int a = 0; a < 2; ++a)
#pragma unroll
    for (int nt = 0; nt < 5; ++nt) acc2[a][nt] = {0.f, 0.f, 0.f, 0.f};
#pragma unroll
  for (int ks = 0; ks < 2; ++ks)
#pragma unroll
    for (int a = 0; a < 2; ++a)
#pragma unroll
      for (int nt = 0; nt < 5; ++nt)
        acc2[a][nt] = __builtin_amdgcn_mfma_f32_16x16x32_bf16(fa2[ks][a], fb2[ks][nt], acc2[a][nt], 0, 0, 0);
  __syncthreads();   // all Aat reads done before wms overwrite

#pragma unroll
  for (int a = 0; a < 2; ++a)
#pragma unroll
    for (int nt = 0; nt < 5; ++nt)
#pragma unroll
      for (int r = 0; r < 4; ++r)
        wms[(oq * 64 + nh * 32 + a * 16 + quad * 4 + r) * 81 + nt * 16 + col] = acc2[a][nt][r];
  __syncthreads();

  // ---- phase 4: softmax, one row per thread (256 rows = 64 n x 4 g) ----
  if (t < 256) {
    int g2 = t >> 6;
    int n_glob = n0 + (t & 63);
    int bg = b * 4 + g2;
    if (g2 < 2) softmax_write<5>(wms, rpb_s + g2 * 81,              attnL, bg, n_glob, t);
    else        softmax_write<7>(wms, rpb_s + 162 + (g2 - 2) * 169, attnL, bg, n_glob, t);
  }
}

// ---------------- K-out: bf16 MFMA 1x1 conv, 128x64 tile, BK=64, 2 blocks/CU ----------------
// MODE 1: B = midT planar [b*4+g][n][64]; out fp32 [o][n] + BN affine.
// BK=64: 4 K-steps (half the barriers of BK=32), same k-accumulation order -> bit-identical.
template <int MODE>
__global__ __launch_bounds__(256, 2)
void conv_mfma_kernel(const __bf16* __restrict__ Wb, const __bf16* __restrict__ Xin,
                      void* __restrict__ Yout, float* __restrict__ stats,
                      const float* __restrict__ bn_g, const float* __restrict__ bn_b) {
  int b  = blockIdx.z;
  int n0 = blockIdx.x * 64;
  int o0 = blockIdx.y * 128;
  __shared__ __bf16 As[128 * 72];   // [m][72] (64 k + 8 pad) = 18432 B
  __shared__ __bf16 Bs[64 * 72];    // [n][72]                =  9216 B
  int t = threadIdx.x;
  int lane = t & 63, wv = t >> 6;
  int mq = (wv & 1) * 64, nq = (wv >> 1) * 32;
  int col = lane & 15, quad = lane >> 4;
  floatx4 acc[4][2];
#pragma unroll
  for (int i = 0; i < 4; ++i)
#pragma unroll
    for (int j = 0; j < 2; ++j) acc[i][j] = {0.f, 0.f, 0.f, 0.f};
  int sm = t >> 1, skA = (t & 1) * 32;     // A: 128 rows x 32 elems
  int snB = t >> 2, kB16 = (t & 3) * 16;   // B: 64 rows x 16 elems
  const __bf16* wp = Wb + (size_t)(o0 + sm) * 256 + skA;
  auto xaddr = [&](int c0) -> const __bf16* {
    if (MODE == 0) {
      return Xin + ((size_t)b * 4096 + n0 + snB) * 256 + c0 + kB16;
    } else {
      int c = c0 + kB16, g = c >> 6, c64 = c & 63;   // 16-elem load stays in-plane (c64<=48)
      return Xin + (((size_t)(b * 4 + g)) * 4096 + n0 + snB) * 64 + c64;
    }
  };
  bf16x8 wa0 = *(const bf16x8*)wp;
  bf16x8 wa1 = *(const bf16x8*)(wp + 8);
  bf16x8 wa2 = *(const bf16x8*)(wp + 16);
  bf16x8 wa3 = *(const bf16x8*)(wp + 24);
  const __bf16* x0 = xaddr(0);
  bf16x8 xb0 = *(const bf16x8*)x0;
  bf16x8 xb1 = *(const bf16x8*)(x0 + 8);
  for (int c0 = 0; c0 < 256; c0 += 64) {
    *(bf16x8*)&As[sm * 72 + skA]      = wa0;
    *(bf16x8*)&As[sm * 72 + skA + 8]  = wa1;
    *(bf16x8*)&As[sm * 72 + skA + 16] = wa2;
    *(bf16x8*)&As[sm * 72 + skA + 24] = wa3;
    *(bf16x8*)&Bs[snB * 72 + kB16]     = xb0;
    *(bf16x8*)&Bs[snB * 72 + kB16 + 8] = xb1;
    __syncthreads();
    if (c0 + 64 < 256) {               // prefetch next K-tile; hides under 16 MFMA
      wa0 = *(const bf16x8*)(wp + c0 + 64);
      wa1 = *(const bf16x8*)(wp + c0 + 72);
      wa2 = *(const bf16x8*)(wp + c0 + 80);
      wa3 = *(const bf16x8*)(wp + c0 + 88);
      const __bf16* xn = xaddr(c0 + 64);
      xb0 = *(const bf16x8*)xn;
      xb1 = *(const bf16x8*)(xn + 8);
    }
    bf16x8 fa[2][4], fb[2][2];
#pragma unroll
    for (int ks = 0; ks < 2; ++ks) {
#pragma unroll
      for (int i = 0; i < 4; ++i)
        fa[ks][i] = *(const bf16x8*)&As[(mq + i * 16 + col) * 72 + ks * 32 + quad * 8];
#pragma unroll
      for (int j = 0; j < 2; ++j)
        fb[ks][j] = *(const bf16x8*)&Bs[(nq + j * 16 + col) * 72 + ks * 32 + quad * 8];
    }
#pragma unroll
    for (int ks = 0; ks < 2; ++ks)
#pragma unroll
      for (int i = 0; i < 4; ++i)
#pragma unroll
        for (int j = 0; j < 2; ++j)
          acc[i][j] = __builtin_amdgcn_mfma_f32_16x16x32_bf16(fa[ks][i], fb[ks][j], acc[i][j], 0, 0, 0);
    __syncthreads();
  }
  {
    float* Yf = (float*)Yout + (size_t)b * 256 * 4096;
#pragma unroll
    for (int i = 0; i < 4; ++i) {
#pragma unroll
      for (int r = 0; r < 4; ++r) {
        int o = o0 + mq + i * 16 + quad * 4 + r;
        float scale = bn_g[o] * 0.9999950000374997f;  // rsqrt(1 + 1e-5)
        float shift = bn_b[o];
        float* yrow = Yf + (size_t)o * 4096 + n0 + nq + col;
#pragma unroll
        for (int j = 0; j < 2; ++j) yrow[j * 16] = acc[i][j][r] * scale + shift;
      }
    }
  }
}

// ------- K5: na2d AV, f32-staged LDS slab (cvt-once), 512 thr / 8-h slab (R6 proven) -------
template <int KK>
DEV void na2d_body8(const __bf16* __restrict__ attnL, const __bf16* __restrict__ XT,
                    __bf16* __restrict__ midT, float* xs, int bg, int h0, int chalf, int t) {
  constexpr int CNT = KK * KK, KC = KK / 2, SMAX = 64 - KK;
  constexpr int ROWS = KK + 7;
  constexpr int PW = (KK == 5) ? 32 : 56;
  int b = bg >> 2, g = bg & 3;
  int si0 = min(max(h0 - KC, 0), SMAX);
  // stage ROWS rows of the 32-ch half into LDS as f32 (convert once)
  {
    int sn = t & 63, sc8 = (t >> 6) & 3, rh = t >> 8;
    const __bf16* src = XT + ((size_t)b * 4096 + sn) * 256 + g * 64 + chalf * 32 + sc8 * 8;
    for (int r = rh; r < ROWS; r += 2) {
      int gr = min(si0 + r, 63);
      bf16x8 v = *(const bf16x8*)(src + (size_t)gr * 64 * 256);
      float f[8];
#pragma unroll
      for (int e = 0; e < 8; ++e) f[e] = (float)v[e];
      float* d = &xs[(r * 64 + sn) * 36 + sc8 * 8];
      *(float4*)d       = *(float4*)&f[0];
      *(float4*)(d + 4) = *(float4*)&f[4];
    }
  }
  __syncthreads();
  int w = t & 63, cg = (t >> 6) & 3, hh = t >> 8;
  int sj = min(max(w - KC, 0), SMAX);
#pragma unroll
  for (int h4 = 0; h4 < 4; ++h4) {
    int h = h0 + hh * 4 + h4;
    int base = min(max(h - KC, 0), SMAX) - si0;
    bf16x8 avh[PW / 8];
    const __bf16* ap = attnL + ((size_t)bg * 4096 + h * 64 + w) * 56;
#pragma unroll
    for (int i = 0; i < PW / 8; ++i) avh[i] = *(const bf16x8*)(ap + i * 8);
    float av[CNT];
#pragma unroll
    for (int m = 0; m < CNT; ++m) av[m] = (float)avh[m / 8][m % 8];
    float acc[8] = {};
#pragma unroll
    for (int p = 0; p < KK; ++p) {
      const float* xr = &xs[((base + p) * 64 + sj) * 36 + cg * 8];
#pragma unroll
      for (int q = 0; q < KK; ++q) {
        float4 v0 = *(const float4*)(xr + q * 36);
        float4 v1 = *(const float4*)(xr + q * 36 + 4);
        float a = av[p * KK + q];
        acc[0] += a * v0.x; acc[1] += a * v0.y; acc[2] += a * v0.z; acc[3] += a * v0.w;
        acc[4] += a * v1.x; acc[5] += a * v1.y; acc[6] += a * v1.z; acc[7] += a * v1.w;
      }
    }
    __bf16 hv[8];
#pragma unroll
    for (int e = 0; e < 8; ++e) hv[e] = (__bf16)acc[e];
    *(bf16x8*)&midT[((size_t)bg * 4096 + h * 64 + w) * 64 + chalf * 32 + cg * 8] = *(bf16x8*)hv;
  }
}

__global__ __launch_bounds__(512, 1)
void na2d_kernel(const __bf16* __restrict__ attnL, const __bf16* __restrict__ XT,
                 __bf16* __restrict__ midT) {
  __shared__ float xs[14 * 64 * 36];   // 129 KB (KK=7 uses 14 rows, KK=5 uses 12)
  int bg = blockIdx.x, h0 = blockIdx.y * 8, chalf = blockIdx.z, t = threadIdx.x;
  if ((bg & 3) < 2) na2d_body8<5>(attnL, XT, midT, xs, bg, h0, chalf, t);
  else              na2d_body8<7>(attnL, XT, midT, xs, bg, h0, chalf, t);
}

// ---------------- launch ----------------
extern "C" void kernel_launch(void* const* d_in, const int* in_sizes, int n_in,
                              void* d_out, int out_size, void* d_ws, size_t ws_size,
                              hipStream_t stream) {
  const float* x     = (const float*)d_in[0];
  const float* ctx   = (const float*)d_in[1];
  const float* Wq    = (const float*)d_in[2];
  const float* gq    = (const float*)d_in[3];
  const float* bq    = (const float*)d_in[4];
  const float* Wk    = (const float*)d_in[5];
  const float* gk    = (const float*)d_in[6];
  const float* bk    = (const float*)d_in[7];
  const float* Wproj = (const float*)d_in[8];
  const float* rpb1  = (const float*)d_in[9];
  const float* rpb2  = (const float*)d_in[10];
  const float* Wdy   = (const float*)d_in[11];
  const float* bn_g  = (const float*)d_in[12];
  const float* bn_b  = (const float*)d_in[13];
  float* out = (float*)d_out;

  float* ws     = (float*)d_ws;
  float* kctx   = ws;                          // 50176 f
  float* kf     = kctx + 50176;                // 50176 f
  __bf16* attnL = (__bf16*)(kf + 50176);       // 16*4096*56 = 3670016 bf16
  __bf16* wqb   = attnL + 3670016;             // 65536 bf16
  __bf16* wdyb  = wqb + 65536;                 // 65536 bf16
  __bf16* kfpT  = wdyb + 65536;                // 16*80*64 = 81920 bf16
  __bf16* XT    = kfpT + 81920;                // 4194304 bf16
  __bf16* midT  = XT + 4194304;                // 4194304 bf16 (planar [bg][n][64])

  prep_kernel<<<dim3(1536), dim3(256), 0, stream>>>(Wq, Wdy, ctx, x, wqb, wdyb, kctx, XT);
  kf_ln_kernel<<<dim3(196), dim3(256), 0, stream>>>(kctx, Wk, gk, bk, kf);
  kfp_kernel<<<dim3(16, 5), dim3(256), 0, stream>>>(kf, Wproj, kfpT);
  qattn_kernel<<<dim3(64, 1, 4), dim3(512), 0, stream>>>(wqb, XT, kfpT, gq, bq, rpb1, rpb2, attnL);
  na2d_kernel<<<dim3(16, 8, 2), dim3(512), 0, stream>>>(attnL, XT, midT);
  conv_mfma_kernel<1><<<dim3(64, 2, 4), dim3(256), 0, stream>>>(wdyb, midT, out, nullptr, bn_g, bn_b);
}

// Round 10
// 153.569 us; speedup vs baseline: 1.0639x; 1.0043x over previous
//
#include <hip/hip_runtime.h>

#define DEV __device__ __forceinline__

typedef __bf16 bf16x8 __attribute__((ext_vector_type(8)));
typedef __bf16 bf16x4 __attribute__((ext_vector_type(4)));
typedef float floatx4 __attribute__((ext_vector_type(4)));

// ---------------- K0: fused prep: cvt weights + pool ctx + transpose x ----
// vectorized: float4 reads everywhere, bf16x8 stores in the transpose.
__global__ __launch_bounds__(256)
void prep_kernel(const float* __restrict__ Wq, const float* __restrict__ Wdy,
                 const float* __restrict__ ctx, const float* __restrict__ x,
                 __bf16* __restrict__ wqb, __bf16* __restrict__ wdyb,
                 float* __restrict__ kctx, __bf16* __restrict__ xt) {
  __shared__ float tile[64][67];         // pad 67: read-phase banks (24a+3e+n)%32 ~2-way
  int bid = blockIdx.x, t = threadIdx.x;
  if (bid < 64) {                        // weight cvt, float4
    int i = bid * 1024 + t * 4;
    float4 a = *(const float4*)(Wq + i);
    float4 d = *(const float4*)(Wdy + i);
    __bf16 ha[4] = {(__bf16)a.x, (__bf16)a.y, (__bf16)a.z, (__bf16)a.w};
    __bf16 hd[4] = {(__bf16)d.x, (__bf16)d.y, (__bf16)d.z, (__bf16)d.w};
    *(bf16x4*)&wqb[i]  = *(bf16x4*)ha;
    *(bf16x4*)&wdyb[i] = *(bf16x4*)hd;
  } else if (bid < 320) {                // pool ctx 56x56 -> 7x7, one wave per (b,c)
    int bc = (bid - 64) * 4 + (t >> 6);
    const float* src = ctx + (size_t)bc * (56 * 56);
    int w = t & 63;
#pragma unroll
    for (int pi = 0; pi < 7; ++pi) {
      float s = 0.f;
      if (w < 56) {
#pragma unroll
        for (int di = 0; di < 8; ++di) s += src[(pi * 8 + di) * 56 + w];
      }
      s += __shfl_down(s, 4);
      s += __shfl_down(s, 2);
      s += __shfl_down(s, 1);
      if (w < 56 && (w & 7) == 0)
        kctx[(size_t)bc * 49 + pi * 7 + (w >> 3)] = s * (1.f / 64.f);
    }
  } else {                               // XT[b][n][c] = bf16(x[b][c][n])
    int idx = bid - 320;
    int b = idx >> 8, c0 = ((idx >> 6) & 3) * 64, n0 = (idx & 63) * 64;
    const float* src = x + ((size_t)b * 256 + c0) * 4096 + n0;
    int cr = t >> 4, nl = (t & 15) * 4;
#pragma unroll
    for (int p = 0; p < 4; ++p) {        // float4 loads: 4 instead of 16 scalars
      int c = p * 16 + cr;
      float4 v = *(const float4*)(src + (size_t)c * 4096 + nl);
      tile[c][nl]     = v.x;
      tile[c][nl + 1] = v.y;
      tile[c][nl + 2] = v.z;
      tile[c][nl + 3] = v.w;
    }
    __syncthreads();
    __bf16* dst = xt + ((size_t)b * 4096 + n0) * 256 + c0;
    int c8 = (t & 7) * 8;
#pragma unroll
    for (int p = 0; p < 2; ++p) {        // bf16x8 16B stores: 2 instead of 16x2B
      int n = p * 32 + (t >> 3);
      __bf16 hv[8];
#pragma unroll
      for (int e = 0; e < 8; ++e) hv[e] = (__bf16)tile[c8 + e][n];
      *(bf16x8*)(dst + (size_t)n * 256 + c8) = *(bf16x8*)hv;
    }
  }
}

// ---------------- K2: kf = LN(Wk @ kctx) per (b,l) ----------------
__global__ __launch_bounds__(256)
void kf_ln_kernel(const float* __restrict__ kctx, const float* __restrict__ Wk,
                  const float* __restrict__ gk, const float* __restrict__ bk,
                  float* __restrict__ kf) {
  int b = blockIdx.x / 49, l = blockIdx.x % 49;
  __shared__ float xs[256];
  __shared__ float r1[4], r2[4];
  int o = threadIdx.x;
  xs[o] = kctx[((size_t)b * 256 + o) * 49 + l];
  __syncthreads();
  const float* wrow = Wk + (size_t)o * 256;
  float acc = 0.f;
#pragma unroll 8
  for (int c = 0; c < 256; c += 4) {
    float4 wv = *(const float4*)(wrow + c);
    acc += wv.x * xs[c] + wv.y * xs[c + 1] + wv.z * xs[c + 2] + wv.w * xs[c + 3];
  }
  float s1 = acc, s2 = acc * acc;
#pragma unroll
  for (int off = 32; off > 0; off >>= 1) {
    s1 += __shfl_down(s1, off);
    s2 += __shfl_down(s2, off);
  }
  int wv_ = o >> 6, ln = o & 63;
  if (ln == 0) { r1[wv_] = s1; r2[wv_] = s2; }
  __syncthreads();
  float mu  = (r1[0] + r1[1] + r1[2] + r1[3]) * (1.f / 256.f);
  float var = (r2[0] + r2[1] + r2[2] + r2[3]) * (1.f / 256.f) - mu * mu;
  float rstd = rsqrtf(var + 1e-6f);
  kf[((size_t)b * 256 + o) * 49 + l] = (acc - mu) * rstd * gk[o] + bk[o];
}

// ------- K2b: kfpT[bg][m(80)][d(64)] = bf16( sum_l kf[b][g*64+d][l] * Wproj[m][l] ) -------
__global__ __launch_bounds__(256)
void kfp_kernel(const float* __restrict__ kf, const float* __restrict__ Wproj,
                __bf16* __restrict__ kfpT) {
  int bg = blockIdx.x; int b = bg >> 2, g = bg & 3;
  int m0 = blockIdx.y * 16;
  __shared__ float kfs[64][50];
  __shared__ float wps[16][50];
  int t = threadIdx.x;
  for (int i = t; i < 64 * 49; i += 256) {
    int d = i / 49, l = i % 49;
    kfs[d][l] = kf[((size_t)b * 256 + g * 64 + d) * 49 + l];
  }
  for (int i = t; i < 16 * 49; i += 256) {
    int m = i / 49, l = i % 49;
    wps[m][l] = (m0 + m < 74) ? Wproj[(m0 + m) * 49 + l] : 0.f;
  }
  __syncthreads();
  for (int i = t; i < 64 * 16; i += 256) {
    int d = i >> 4, m = i & 15;
    float s = 0.f;
    if (m0 + m < 74) {
#pragma unroll 7
      for (int l = 0; l < 49; ++l) s += kfs[d][l] * wps[m][l];
    }
    kfpT[(size_t)bg * 5120 + (m0 + m) * 64 + d] = (__bf16)s;
  }
}

// ---------------- softmax helpers (unchanged, proven) ----------------
DEV int rep_idx(int p, int kc, int t1, int sub) {
  return p < kc ? p : (p < t1 ? kc : p - sub);
}

template <int KK>
DEV void softmax_write(const float* wms, const float* rpb_s, __bf16* __restrict__ attnL,
                       int bg, int n_glob, int row) {
  constexpr int CNT = KK * KK;
  constexpr int RS  = 2 * KK - 1;
  constexpr int KC  = KK / 2;
  constexpr int T1  = KC + (64 - KK + 1);
  constexpr int SUB = 64 - KK;
  constexpr int MLO = (KK == 5) ? 0 : 25;
  constexpr int PW  = (KK == 5) ? 32 : 56;    // padded width (multiple of 8)
  int h = n_glob >> 6, w = n_glob & 63;
  int rh = rep_idx(63 - h, KC, T1, SUB);
  int rw = rep_idx(63 - w, KC, T1, SUB);
  float vals[CNT];
  float mx = -1e30f;
#pragma unroll
  for (int m = 0; m < CNT; ++m) {
    int ki = m / KK, kj = m % KK;
    float v = wms[row * 81 + MLO + m] + rpb_s[(rh + ki) * RS + rw + kj];
    vals[m] = v; mx = fmaxf(mx, v);
  }
  float ssum = 0.f;
#pragma unroll
  for (int m = 0; m < CNT; ++m) { float e = __expf(vals[m] - mx); vals[m] = e; ssum += e; }
  float inv = 1.f / ssum;
  __bf16 hv[PW];
#pragma unroll
  for (int m = 0; m < PW; ++m) hv[m] = (__bf16)(m < CNT ? vals[m] * inv : 0.f);
  __bf16* ap = attnL + ((size_t)bg * 4096 + n_glob) * 56;
#pragma unroll
  for (int i = 0; i < PW / 8; ++i) *(bf16x8*)(ap + i * 8) = *(bf16x8*)&hv[i * 8];
}

// ---------------- K3: fused q-GEMM + LN + QK-proj MFMA + softmax (512 thr, 8 waves) ----
// Phase 1: BK=64, DOUBLE-BUFFERED As/Bs -> 1 barrier/K-step (was 2); ds_writes of
// tile k+1 co-schedule with iter k MFMA. Same MFMA order -> bit-identical.
__global__ __launch_bounds__(512, 1)
void qattn_kernel(const __bf16* __restrict__ Wb, const __bf16* __restrict__ XT,
                  const __bf16* __restrict__ kfpT,
                  const float* __restrict__ gq, const float* __restrict__ bq,
                  const float* __restrict__ rpb1, const float* __restrict__ rpb2,
                  __bf16* __restrict__ attnL) {
  __shared__ __align__(16) float smem[23040];  // 92.2 KB: dbuf As/Bs; reused as Aat/wms
  __shared__ float rpb_s[500];           // rpb1 [0..161], rpb2 [162..499]
  __shared__ float gqs[256], bqs[256];
  __shared__ float red_s[4][64], red_q[4][64];
  __shared__ float st_mu[64], st_rs[64];
  float* wms  = smem;                    // [256 rows][81] f32 (phase 3b/4)
  __bf16* Aat = (__bf16*)smem;           // [4 g][64 n][72 d] (phase 3)
  __bf16* Ab0 = (__bf16*)smem;           // buf0: As[256][72] + Bs[64][72]
  __bf16* Ab1 = (__bf16*)smem + 23040;   // buf1

  int b  = blockIdx.z;
  int n0 = blockIdx.x * 64;
  int t  = threadIdx.x;
  int lane = t & 63, wv = t >> 6;
  int oq = wv & 3, nh = wv >> 2;         // o-quadrant, n-half
  int col = lane & 15, quad = lane >> 4;

  if (t < 256) {
    gqs[t] = gq[t] * 0.125f;             // SCALE folded
    bqs[t] = bq[t] * 0.125f;
  }
  for (int i = t; i < 162; i += 512) rpb_s[i] = rpb1[i];
  for (int i = t; i < 338; i += 512) rpb_s[162 + i] = rpb2[i];

  // ---- phase 1: q = Wq @ x, M=256(o) x N=64(n) x K=256, BK=64, dbuf ----
  floatx4 acc[4][2];
#pragma unroll
  for (int i = 0; i < 4; ++i)
#pragma unroll
    for (int j = 0; j < 2; ++j) acc[i][j] = {0.f, 0.f, 0.f, 0.f};

  int rowA = t >> 1, kA = (t & 1) * 32;        // 256 W rows, 32 elems each
  int rowB = t >> 3, kB = (t & 7) * 8;         // 64 XT rows, 8 elems each
  const __bf16* wp = Wb + (size_t)rowA * 256 + kA;
  const __bf16* xp = XT + ((size_t)b * 4096 + n0 + rowB) * 256 + kB;
  bf16x8 ra0 = *(const bf16x8*)wp;
  bf16x8 ra1 = *(const bf16x8*)(wp + 8);
  bf16x8 ra2 = *(const bf16x8*)(wp + 16);
  bf16x8 ra3 = *(const bf16x8*)(wp + 24);
  bf16x8 rb  = *(const bf16x8*)xp;
  {  // stage tile 0 into buf0
    __bf16* A = Ab0; __bf16* B = Ab0 + 18432;
    *(bf16x8*)&A[rowA * 72 + kA]      = ra0;
    *(bf16x8*)&A[rowA * 72 + kA + 8]  = ra1;
    *(bf16x8*)&A[rowA * 72 + kA + 16] = ra2;
    *(bf16x8*)&A[rowA * 72 + kA + 24] = ra3;
    *(bf16x8*)&B[rowB * 72 + kB]      = rb;
  }
  ra0 = *(const bf16x8*)(wp + 64);     // tile 1 into regs
  ra1 = *(const bf16x8*)(wp + 72);
  ra2 = *(const bf16x8*)(wp + 80);
  ra3 = *(const bf16x8*)(wp + 88);
  rb  = *(const bf16x8*)(xp + 64);
  __syncthreads();                     // buf0 ready

#pragma unroll
  for (int k = 0; k < 4; ++k) {
    __bf16* A = (k & 1) ? Ab1 : Ab0;
    __bf16* B = A + 18432;
    bf16x8 fa[2][4], fb[2][2];
#pragma unroll
    for (int ks = 0; ks < 2; ++ks) {
#pragma unroll
      for (int i = 0; i < 4; ++i)
        fa[ks][i] = *(const bf16x8*)&A[(oq * 64 + i * 16 + col) * 72 + ks * 32 + quad * 8];
#pragma unroll
      for (int j = 0; j < 2; ++j)
        fb[ks][j] = *(const bf16x8*)&B[(nh * 32 + j * 16 + col) * 72 + ks * 32 + quad * 8];
    }
    if (k < 3) {                       // store tile k+1 regs into the other buffer
      __bf16* An = (k & 1) ? Ab0 : Ab1;
      __bf16* Bn = An + 18432;
      *(bf16x8*)&An[rowA * 72 + kA]      = ra0;
      *(bf16x8*)&An[rowA * 72 + kA + 8]  = ra1;
      *(bf16x8*)&An[rowA * 72 + kA + 16] = ra2;
      *(bf16x8*)&An[rowA * 72 + kA + 24] = ra3;
      *(bf16x8*)&Bn[rowB * 72 + kB]      = rb;
    }
    if (k < 2) {                       // prefetch tile k+2
      int cn = (k + 2) * 64;
      ra0 = *(const bf16x8*)(wp + cn);
      ra1 = *(const bf16x8*)(wp + cn + 8);
      ra2 = *(const bf16x8*)(wp + cn + 16);
      ra3 = *(const bf16x8*)(wp + cn + 24);
      rb  = *(const bf16x8*)(xp + cn);
    }
#pragma unroll
    for (int ks = 0; ks < 2; ++ks)
#pragma unroll
      for (int i = 0; i < 4; ++i)
#pragma unroll
        for (int j = 0; j < 2; ++j)
          acc[i][j] = __builtin_amdgcn_mfma_f32_16x16x32_bf16(fa[ks][i], fb[ks][j], acc[i][j], 0, 0, 0);
    if (k < 3) __syncthreads();        // next buffer ready; this buffer's reads drained
  }

  // ---- phase 2: LN stats over o (exact f32) ----
#pragma unroll
  for (int j = 0; j < 2; ++j) {
    float s = 0.f, q = 0.f;
#pragma unroll
    for (int i = 0; i < 4; ++i)
#pragma unroll
      for (int r = 0; r < 4; ++r) { float v = acc[i][j][r]; s += v; q += v * v; }
    s += __shfl_xor(s, 16); s += __shfl_xor(s, 32);   // reduce over quad -> full 64-o
    q += __shfl_xor(q, 16); q += __shfl_xor(q, 32);
    if (quad == 0) {
      red_s[oq][nh * 32 + j * 16 + col] = s;
      red_q[oq][nh * 32 + j * 16 + col] = q;
    }
  }
  __syncthreads();
  if (t < 64) {
    float s = red_s[0][t] + red_s[1][t] + red_s[2][t] + red_s[3][t];
    float q = red_q[0][t] + red_q[1][t] + red_q[2][t] + red_q[3][t];
    float mu  = s * (1.f / 256.f);
    float var = q * (1.f / 256.f) - mu * mu;
    st_mu[t] = mu;
    st_rs[t] = rsqrtf(var + 1e-6f);
  }
  __syncthreads();

  // ---- phase 3: q-hat -> Aat (A-fragment layout), then attn MFMA ----
#pragma unroll
  for (int j = 0; j < 2; ++j) {
    int n_loc = nh * 32 + j * 16 + col;
    float mu = st_mu[n_loc], rs = st_rs[n_loc];
#pragma unroll
    for (int i = 0; i < 4; ++i) {
      __bf16 pk[4];
#pragma unroll
      for (int r = 0; r < 4; ++r) {
        int o = oq * 64 + i * 16 + quad * 4 + r;
        pk[r] = (__bf16)((acc[i][j][r] - mu) * rs * gqs[o] + bqs[o]);
      }
      *(bf16x4*)&Aat[((size_t)(oq * 64 + n_loc)) * 72 + i * 16 + quad * 4] = *(bf16x4*)pk;
    }
  }
  __syncthreads();

  // attn MFMA: per head-group g = oq; 2 waves/g, each 32 n x 80 m x K=64
  bf16x8 fa2[2][2], fb2[2][5];
  const __bf16* kp = kfpT + (size_t)(b * 4 + oq) * 5120;   // L2-hot, 10 KB
#pragma unroll
  for (int ks = 0; ks < 2; ++ks) {
#pragma unroll
    for (int a = 0; a < 2; ++a)
      fa2[ks][a] = *(const bf16x8*)&Aat[((size_t)(oq * 64 + nh * 32 + a * 16 + col)) * 72 + ks * 32 + quad * 8];
#pragma unroll
    for (int nt = 0; nt < 5; ++nt)
      fb2[ks][nt] = *(const bf16x8*)&kp[(nt * 16 + col) * 64 + ks * 32 + quad * 8];
  }
  floatx4 acc2[2][5];
#pragma unroll
  for (int a = 0; a < 2; ++a)
#pragma unroll
    for (int nt = 0; nt < 5; ++nt) acc2[a][nt] = {0.f, 0.f, 0.f, 0.f};
#pragma unroll
  for (int ks = 0; ks < 2; ++ks)
#pragma unroll
    for (int a = 0; a < 2; ++a)
#pragma unroll
      for (int nt = 0; nt < 5; ++nt)
        acc2[a][nt] = __builtin_amdgcn_mfma_f32_16x16x32_bf16(fa2[ks][a], fb2[ks][nt], acc2[a][nt], 0, 0, 0);
  __syncthreads();   // all Aat reads done before wms overwrite

#pragma unroll
  for (int a = 0; a < 2; ++a)
#pragma unroll
    for (int nt = 0; nt < 5; ++nt)
#pragma unroll
      for (int r = 0; r < 4; ++r)
        wms[(oq * 64 + nh * 32 + a * 16 + quad * 4 + r) * 81 + nt * 16 + col] = acc2[a][nt][r];
  __syncthreads();

  // ---- phase 4: softmax, one row per thread (256 rows = 64 n x 4 g) ----
  if (t < 256) {
    int g2 = t >> 6;
    int n_glob = n0 + (t & 63);
    int bg = b * 4 + g2;
    if (g2 < 2) softmax_write<5>(wms, rpb_s + g2 * 81,              attnL, bg, n_glob, t);
    else        softmax_write<7>(wms, rpb_s + 162 + (g2 - 2) * 169, attnL, bg, n_glob, t);
  }
}

// ---------------- K-out: bf16 MFMA 1x1 conv, 128x64 tile, BK=64, dbuf, 2 blocks/CU ----
// MODE 1: B = midT planar [b*4+g][n][64]; out fp32 [o][n] + BN affine.
template <int MODE>
__global__ __launch_bounds__(256, 2)
void conv_mfma_kernel(const __bf16* __restrict__ Wb, const __bf16* __restrict__ Xin,
                      void* __restrict__ Yout, float* __restrict__ stats,
                      const float* __restrict__ bn_g, const float* __restrict__ bn_b) {
  int b  = blockIdx.z;
  int n0 = blockIdx.x * 64;
  int o0 = blockIdx.y * 128;
  __shared__ __align__(16) __bf16 smem[2 * 13824];  // dbuf: As[128][72]+Bs[64][72] x2 = 55.3 KB
  __bf16* Ab0 = smem;
  __bf16* Ab1 = smem + 13824;
  int t = threadIdx.x;
  int lane = t & 63, wv = t >> 6;
  int mq = (wv & 1) * 64, nq = (wv >> 1) * 32;
  int col = lane & 15, quad = lane >> 4;
  floatx4 acc[4][2];
#pragma unroll
  for (int i = 0; i < 4; ++i)
#pragma unroll
    for (int j = 0; j < 2; ++j) acc[i][j] = {0.f, 0.f, 0.f, 0.f};
  int sm = t >> 1, skA = (t & 1) * 32;     // A: 128 rows x 32 elems
  int snB = t >> 2, kB16 = (t & 3) * 16;   // B: 64 rows x 16 elems
  const __bf16* wp = Wb + (size_t)(o0 + sm) * 256 + skA;
  auto xaddr = [&](int c0) -> const __bf16* {
    if (MODE == 0) {
      return Xin + ((size_t)b * 4096 + n0 + snB) * 256 + c0 + kB16;
    } else {
      int c = c0 + kB16, g = c >> 6, c64 = c & 63;   // 16-elem load stays in-plane (c64<=48)
      return Xin + (((size_t)(b * 4 + g)) * 4096 + n0 + snB) * 64 + c64;
    }
  };
  bf16x8 wa0 = *(const bf16x8*)wp;
  bf16x8 wa1 = *(const bf16x8*)(wp + 8);
  bf16x8 wa2 = *(const bf16x8*)(wp + 16);
  bf16x8 wa3 = *(const bf16x8*)(wp + 24);
  const __bf16* x0 = xaddr(0);
  bf16x8 xb0 = *(const bf16x8*)x0;
  bf16x8 xb1 = *(const bf16x8*)(x0 + 8);
  {  // stage tile 0 into buf0
    __bf16* A = Ab0; __bf16* B = Ab0 + 9216;
    *(bf16x8*)&A[sm * 72 + skA]      = wa0;
    *(bf16x8*)&A[sm * 72 + skA + 8]  = wa1;
    *(bf16x8*)&A[sm * 72 + skA + 16] = wa2;
    *(bf16x8*)&A[sm * 72 + skA + 24] = wa3;
    *(bf16x8*)&B[snB * 72 + kB16]     = xb0;
    *(bf16x8*)&B[snB * 72 + kB16 + 8] = xb1;
  }
  wa0 = *(const bf16x8*)(wp + 64);       // tile 1 into regs
  wa1 = *(const bf16x8*)(wp + 72);
  wa2 = *(const bf16x8*)(wp + 80);
  wa3 = *(const bf16x8*)(wp + 88);
  {
    const __bf16* xn = xaddr(64);
    xb0 = *(const bf16x8*)xn;
    xb1 = *(const bf16x8*)(xn + 8);
  }
  __syncthreads();                       // buf0 ready

#pragma unroll
  for (int k = 0; k < 4; ++k) {
    __bf16* A = (k & 1) ? Ab1 : Ab0;
    __bf16* B = A + 9216;
    bf16x8 fa[2][4], fb[2][2];
#pragma unroll
    for (int ks = 0; ks < 2; ++ks) {
#pragma unroll
      for (int i = 0; i < 4; ++i)
        fa[ks][i] = *(const bf16x8*)&A[(mq + i * 16 + col) * 72 + ks * 32 + quad * 8];
#pragma unroll
      for (int j = 0; j < 2; ++j)
        fb[ks][j] = *(const bf16x8*)&B[(nq + j * 16 + col) * 72 + ks * 32 + quad * 8];
    }
    if (k < 3) {                         // store tile k+1 into the other buffer
      __bf16* An = (k & 1) ? Ab0 : Ab1;
      __bf16* Bn = An + 9216;
      *(bf16x8*)&An[sm * 72 + skA]      = wa0;
      *(bf16x8*)&An[sm * 72 + skA + 8]  = wa1;
      *(bf16x8*)&An[sm * 72 + skA + 16] = wa2;
      *(bf16x8*)&An[sm * 72 + skA + 24] = wa3;
      *(bf16x8*)&Bn[snB * 72 + kB16]     = xb0;
      *(bf16x8*)&Bn[snB * 72 + kB16 + 8] = xb1;
    }
    if (k < 2) {                         // prefetch tile k+2
      int cn = (k + 2) * 64;
      wa0 = *(const bf16x8*)(wp + cn);
      wa1 = *(const bf16x8*)(wp + cn + 8);
      wa2 = *(const bf16x8*)(wp + cn + 16);
      wa3 = *(const bf16x8*)(wp + cn + 24);
      const __bf16* xn = xaddr(cn);
      xb0 = *(const bf16x8*)xn;
      xb1 = *(const bf16x8*)(xn + 8);
    }
#pragma unroll
    for (int ks = 0; ks < 2; ++ks)
#pragma unroll
      for (int i = 0; i < 4; ++i)
#pragma unroll
        for (int j = 0; j < 2; ++j)
          acc[i][j] = __builtin_amdgcn_mfma_f32_16x16x32_bf16(fa[ks][i], fb[ks][j], acc[i][j], 0, 0, 0);
    if (k < 3) __syncthreads();
  }
  {
    float* Yf = (float*)Yout + (size_t)b * 256 * 4096;
#pragma unroll
    for (int i = 0; i < 4; ++i) {
#pragma unroll
      for (int r = 0; r < 4; ++r) {
        int o = o0 + mq + i * 16 + quad * 4 + r;
        float scale = bn_g[o] * 0.9999950000374997f;  // rsqrt(1 + 1e-5)
        float shift = bn_b[o];
        float* yrow = Yf + (size_t)o * 4096 + n0 + nq + col;
#pragma unroll
        for (int j = 0; j < 2; ++j) yrow[j * 16] = acc[i][j][r] * scale + shift;
      }
    }
  }
}

// ------- K5: na2d AV, f32-staged LDS slab (cvt-once), 512 thr / 8-h slab (R6 proven) -------
template <int KK>
DEV void na2d_body8(const __bf16* __restrict__ attnL, const __bf16* __restrict__ XT,
                    __bf16* __restrict__ midT, float* xs, int bg, int h0, int chalf, int t) {
  constexpr int CNT = KK * KK, KC = KK / 2, SMAX = 64 - KK;
  constexpr int ROWS = KK + 7;
  constexpr int PW = (KK == 5) ? 32 : 56;
  int b = bg >> 2, g = bg & 3;
  int si0 = min(max(h0 - KC, 0), SMAX);
  // stage ROWS rows of the 32-ch half into LDS as f32 (convert once)
  {
    int sn = t & 63, sc8 = (t >> 6) & 3, rh = t >> 8;
    const __bf16* src = XT + ((size_t)b * 4096 + sn) * 256 + g * 64 + chalf * 32 + sc8 * 8;
    for (int r = rh; r < ROWS; r += 2) {
      int gr = min(si0 + r, 63);
      bf16x8 v = *(const bf16x8*)(src + (size_t)gr * 64 * 256);
      float f[8];
#pragma unroll
      for (int e = 0; e < 8; ++e) f[e] = (float)v[e];
      float* d = &xs[(r * 64 + sn) * 36 + sc8 * 8];
      *(float4*)d       = *(float4*)&f[0];
      *(float4*)(d + 4) = *(float4*)&f[4];
    }
  }
  __syncthreads();
  int w = t & 63, cg = (t >> 6) & 3, hh = t >> 8;
  int sj = min(max(w - KC, 0), SMAX);
#pragma unroll
  for (int h4 = 0; h4 < 4; ++h4) {
    int h = h0 + hh * 4 + h4;
    int base = min(max(h - KC, 0), SMAX) - si0;
    bf16x8 avh[PW / 8];
    const __bf16* ap = attnL + ((size_t)bg * 4096 + h * 64 + w) * 56;
#pragma unroll
    for (int i = 0; i < PW / 8; ++i) avh[i] = *(const bf16x8*)(ap + i * 8);
    float av[CNT];
#pragma unroll
    for (int m = 0; m < CNT; ++m) av[m] = (float)avh[m / 8][m % 8];
    float acc[8] = {};
#pragma unroll
    for (int p = 0; p < KK; ++p) {
      const float* xr = &xs[((base + p) * 64 + sj) * 36 + cg * 8];
#pragma unroll
      for (int q = 0; q < KK; ++q) {
        float4 v0 = *(const float4*)(xr + q * 36);
        float4 v1 = *(const float4*)(xr + q * 36 + 4);
        float a = av[p * KK + q];
        acc[0] += a * v0.x; acc[1] += a * v0.y; acc[2] += a * v0.z; acc[3] += a * v0.w;
        acc[4] += a * v1.x; acc[5] += a * v1.y; acc[6] += a * v1.z; acc[7] += a * v1.w;
      }
    }
    __bf16 hv[8];
#pragma unroll
    for (int e = 0; e < 8; ++e) hv[e] = (__bf16)acc[e];
    *(bf16x8*)&midT[((size_t)bg * 4096 + h * 64 + w) * 64 + chalf * 32 + cg * 8] = *(bf16x8*)hv;
  }
}

__global__ __launch_bounds__(512, 1)
void na2d_kernel(const __bf16* __restrict__ attnL, const __bf16* __restrict__ XT,
                 __bf16* __restrict__ midT) {
  __shared__ float xs[14 * 64 * 36];   // 129 KB (KK=7 uses 14 rows, KK=5 uses 12)
  int bg = blockIdx.x, h0 = blockIdx.y * 8, chalf = blockIdx.z, t = threadIdx.x;
  if ((bg & 3) < 2) na2d_body8<5>(attnL, XT, midT, xs, bg, h0, chalf, t);
  else              na2d_body8<7>(attnL, XT, midT, xs, bg, h0, chalf, t);
}

// ---------------- launch ----------------
extern "C" void kernel_launch(void* const* d_in, const int* in_sizes, int n_in,
                              void* d_out, int out_size, void* d_ws, size_t ws_size,
                              hipStream_t stream) {
  const float* x     = (const float*)d_in[0];
  const float* ctx   = (const float*)d_in[1];
  const float* Wq    = (const float*)d_in[2];
  const float* gq    = (const float*)d_in[3];
  const float* bq    = (const float*)d_in[4];
  const float* Wk    = (const float*)d_in[5];
  const float* gk    = (const float*)d_in[6];
  const float* bk    = (const float*)d_in[7];
  const float* Wproj = (const float*)d_in[8];
  const float* rpb1  = (const float*)d_in[9];
  const float* rpb2  = (const float*)d_in[10];
  const float* Wdy   = (const float*)d_in[11];
  const float* bn_g  = (const float*)d_in[12];
  const float* bn_b  = (const float*)d_in[13];
  float* out = (float*)d_out;

  float* ws     = (float*)d_ws;
  float* kctx   = ws;                          // 50176 f
  float* kf     = kctx + 50176;                // 50176 f
  __bf16* attnL = (__bf16*)(kf + 50176);       // 16*4096*56 = 3670016 bf16
  __bf16* wqb   = attnL + 3670016;             // 65536 bf16
  __bf16* wdyb  = wqb + 65536;                 // 65536 bf16
  __bf16* kfpT  = wdyb + 65536;                // 16*80*64 = 81920 bf16
  __bf16* XT    = kfpT + 81920;                // 4194304 bf16
  __bf16* midT  = XT + 4194304;                // 4194304 bf16 (planar [bg][n][64])

  prep_kernel<<<dim3(1344), dim3(256), 0, stream>>>(Wq, Wdy, ctx, x, wqb, wdyb, kctx, XT);
  kf_ln_kernel<<<dim3(196), dim3(256), 0, stream>>>(kctx, Wk, gk, bk, kf);
  kfp_kernel<<<dim3(16, 5), dim3(256), 0, stream>>>(kf, Wproj, kfpT);
  qattn_kernel<<<dim3(64, 1, 4), dim3(512), 0, stream>>>(wqb, XT, kfpT, gq, bq, rpb1, rpb2, attnL);
  na2d_kernel<<<dim3(16, 8, 2), dim3(512), 0, stream>>>(attnL, XT, midT);
  conv_mfma_kernel<1><<<dim3(64, 2, 4), dim3(256), 0, stream>>>(wdyb, midT, out, nullptr, bn_g, bn_b);
}